// Round 8
// baseline (30.161 us; speedup 1.0000x reference)
//
#include <hip/hip_runtime.h>

// TwoBodySplineScalarEmbed: out[e,c] = sum_b basis(x[e])_b * coeffs[cls[e], b, c]
// Quadratic uniform B-spline on [0,1], grid=5, NUM_BASIS=6; only 3 weights nonzero:
//   i0 = clamp(floor(4x),0,3), u = 4x-i0
//   w0 = (1-u)^2/2, w1 = -u^2+u+1/2, w2 = u^2/2   at basis rows i0..i0+2
//
// R7: no LDS at all. The 24 KiB coeff table is L1-resident (32 KiB L1/CU), so
// coeff rows are read directly from global (L1 hits after warmup). No staging,
// no barriers, no LDS occupancy cap -> 8 blocks/CU (32 waves/CU, max) and a
// minimal dependency chain per iteration. Tests the latency-hiding-depth
// hypothesis for the 27 us wall.
constexpr int NUM_TYPES = 4;
constexpr int NUM_BASIS = 6;
constexpr int CHANNELS  = 64;

typedef float f4 __attribute__((ext_vector_type(4)));

__global__ __launch_bounds__(256)
void TwoBodySplineScalarEmbed_kernel(const float* __restrict__ x,
                                     const int*   __restrict__ edge_types,
                                     const float* __restrict__ coeffs,
                                     float*       __restrict__ out,
                                     int E)
{
    const int laneC  = threadIdx.x & 15;   // which float4 of the 64 channels
    const int grp    = threadIdx.x >> 4;   // 0..15: group index within block
    const int stride = gridDim.x << 4;     // total 16-lane groups in grid

    for (int e = (blockIdx.x << 4) + grp; e < E; e += stride)
    {
        float xj = fminf(fmaxf(x[e], 0.0f), 1.0f - 1e-6f);
        float s  = xj * 4.0f;
        int   i0 = (int)s;  i0 = i0 > 3 ? 3 : i0;
        float u  = s - (float)i0;
        float omu = 1.0f - u;
        float w0 = 0.5f * omu * omu;
        float w1 = u * omu + 0.5f;
        float w2 = 0.5f * u * u;

        int row = (edge_types[e] * NUM_TYPES + edge_types[E + e]) * NUM_BASIS + i0;
        const f4* bp = reinterpret_cast<const f4*>(coeffs + row * CHANNELS) + laneC;
        f4 r0 = bp[0];                       // +0   bytes within row
        f4 r1 = bp[CHANNELS / 4];            // +256 (next basis row)
        f4 r2 = bp[CHANNELS / 2];            // +512

        f4 o = w0 * r0 + w1 * r1 + w2 * r2;
        *reinterpret_cast<f4*>(out + (size_t)e * CHANNELS + laneC * 4) = o;
    }
}

extern "C" void kernel_launch(void* const* d_in, const int* in_sizes, int n_in,
                              void* d_out, int out_size, void* d_ws, size_t ws_size,
                              hipStream_t stream)
{
    const float* x          = (const float*)d_in[0];
    const int*   edge_types = (const int*)d_in[1];
    const float* coeffs     = (const float*)d_in[2];
    float*       out        = (float*)d_out;

    const int E = in_sizes[0];

    // No LDS -> 8 blocks/CU co-resident; 2048 blocks = 32768 groups,
    // 15-16 grid-stride iterations per group (<5% imbalance).
    int grid = (E + 15) / 16;
    if (grid > 2048) grid = 2048;

    TwoBodySplineScalarEmbed_kernel<<<grid, 256, 0, stream>>>(
        x, edge_types, coeffs, out, E);
}

// Round 9
// 27.232 us; speedup vs baseline: 1.1075x; 1.1075x over previous
//
#include <hip/hip_runtime.h>

// TwoBodySplineScalarEmbed: out[e,c] = sum_b basis(x[e])_b * coeffs[cls[e], b, c]
// Quadratic uniform B-spline on [0,1], grid=5, NUM_BASIS=6; only 3 weights nonzero:
//   i0 = clamp(floor(4x),0,3), u = 4x-i0
//   w0 = (1-u)^2/2, w1 = -u^2+u+1/2, w2 = u^2/2   at basis rows i0..i0+2
//
// Final (best-measured) variant = R5 structure: coeff table + all per-edge
// inputs staged to LDS in coalesced bursts; main loop is a pure store stream
// (LDS reads + global stores only). Measured 27.0 us; seven structurally
// distinct variants all landed 27.0-30.2 us while the harness fill kernel
// sustains ~6.7 TB/s -> kernel GPU time ~=20-22 us (HBM write roofline for
// the irreducible 128 MB output + 6 MB inputs), residual is fixed per-replay
// dispatch overhead.
constexpr int NUM_TYPES    = 4;
constexpr int NUM_BASIS    = 6;
constexpr int CHANNELS     = 64;
constexpr int COEFF_FLOATS = NUM_TYPES * NUM_TYPES * NUM_BASIS * CHANNELS; // 6144 (24 KiB)
constexpr int KMAX  = 21;          // max inner iterations per staging pass
constexpr int SLOTS = 16 * KMAX;   // 336 edges staged per block per pass

typedef float f4 __attribute__((ext_vector_type(4)));

__global__ __launch_bounds__(256)
void TwoBodySplineScalarEmbed_kernel(const float* __restrict__ x,
                                     const int*   __restrict__ edge_types,
                                     const float* __restrict__ coeffs,
                                     float*       __restrict__ out,
                                     int E)
{
    __shared__ float          sc[COEFF_FLOATS];
    __shared__ float          sx[SLOTS];
    __shared__ unsigned short srow[SLOTS];   // cls * NUM_BASIS (fits in u16)
    // total LDS: 24576 + 1344 + 672 = 26592 B -> 6 blocks/CU

    // Stage coefficient table (vectorized: 1536 f4 = 256 threads x 6).
    #pragma unroll
    for (int i = 0; i < COEFF_FLOATS / 4 / 256; ++i) {
        int idx = threadIdx.x + i * 256;
        reinterpret_cast<f4*>(sc)[idx] = reinterpret_cast<const f4*>(coeffs)[idx];
    }

    const int laneC  = threadIdx.x & 15;   // which float4 of the 64 channels
    const int grp    = threadIdx.x >> 4;   // 0..15: group index within block
    const int c0     = laneC * 4;
    const int stride = gridDim.x << 4;     // edges consumed per inner iteration
    const int t      = threadIdx.x;

    for (int base = blockIdx.x << 4; base < E; base += stride * KMAX)
    {
        // Stage this pass's inputs: slot s = k*16 + g  ->  edge = base + g + k*stride.
        for (int s = t; s < SLOTS; s += 256) {
            int e = base + (s & 15) + (s >> 4) * stride;
            if (e < E) {
                sx[s]   = x[e];
                srow[s] = (unsigned short)((edge_types[e] * NUM_TYPES +
                                            edge_types[E + e]) * NUM_BASIS);
            }
        }
        __syncthreads();

        // Pure-store main loop: only LDS reads + global stores.
        for (int k = 0; k < KMAX; ++k) {
            int e = base + grp + k * stride;
            if (e >= E) break;
            int s = (k << 4) + grp;

            float xj = fminf(fmaxf(sx[s], 0.0f), 1.0f - 1e-6f);
            float sx4 = xj * 4.0f;
            int   i0  = (int)sx4;  i0 = i0 > 3 ? 3 : i0;
            float u   = sx4 - (float)i0;
            float omu = 1.0f - u;
            float w0 = 0.5f * omu * omu;
            float w1 = u * omu + 0.5f;
            float w2 = 0.5f * u * u;

            const float* bp = &sc[(srow[s] + i0) * CHANNELS + c0];
            f4 r0 = *reinterpret_cast<const f4*>(bp);
            f4 r1 = *reinterpret_cast<const f4*>(bp + CHANNELS);
            f4 r2 = *reinterpret_cast<const f4*>(bp + 2 * CHANNELS);

            f4 o = w0 * r0 + w1 * r1 + w2 * r2;
            *reinterpret_cast<f4*>(out + (size_t)e * CHANNELS + c0) = o;
        }
        __syncthreads();   // protect sx/srow before next pass overwrites (multi-pass only)
    }
}

extern "C" void kernel_launch(void* const* d_in, const int* in_sizes, int n_in,
                              void* d_out, int out_size, void* d_ws, size_t ws_size,
                              hipStream_t stream)
{
    const float* x          = (const float*)d_in[0];
    const int*   edge_types = (const int*)d_in[1];
    const float* coeffs     = (const float*)d_in[2];
    float*       out        = (float*)d_out;

    const int E = in_sizes[0];

    // 26.0 KiB LDS/block -> 6 blocks/CU resident; 256 CU * 6 = 1536 co-resident.
    int grid = (E + 15) / 16;
    if (grid > 1536) grid = 1536;

    TwoBodySplineScalarEmbed_kernel<<<grid, 256, 0, stream>>>(
        x, edge_types, coeffs, out, E);
}